// Round 6
// baseline (1160.802 us; speedup 1.0000x reference)
//
#include <hip/hip_runtime.h>

#define TPB 256
#define HOR 28
#define LOG2E 1.44269504088896340736f

typedef _Float16 f16;
typedef __attribute__((ext_vector_type(2))) _Float16 f16x2;
typedef __attribute__((ext_vector_type(4))) _Float16 f16x4;
typedef __attribute__((ext_vector_type(8))) _Float16 f16x8;
typedef __attribute__((ext_vector_type(4))) float f32x4;

union V8 { f16x8 v8; f16x4 v4[2]; f16x2 h2[4]; };

#define MFMA16(A,B,C) __builtin_amdgcn_mfma_f32_16x16x32_f16((A),(B),(C),0,0,0)

__device__ __forceinline__ f16x2 pk2(float a, float b) {
    return __builtin_bit_cast(f16x2, __builtin_amdgcn_cvt_pkrtz(a, b));
}

__global__ __launch_bounds__(TPB, 4) void predictor_kernel(
    const float* __restrict__ features,
    const float* __restrict__ last_value,
    const float* __restrict__ W_ih,
    const float* __restrict__ W_hh,
    const float* __restrict__ b_ih,
    const float* __restrict__ b_hh,
    const float* __restrict__ Wp,
    const float* __restrict__ bp,
    const float* __restrict__ Wo1,
    const float* __restrict__ bo1,
    const float* __restrict__ Wo2,
    const float* __restrict__ bo2,
    const float* __restrict__ Wg1,
    const float* __restrict__ bg1,
    const float* __restrict__ Wg2,
    const float* __restrict__ bg2,
    const float* __restrict__ log_decay,
    float* __restrict__ out)
{
    // 32256-element f16 union region (32.3 KB -> 4 blocks/CU):
    //  phase1: s_wp[64*136]=8704 | s_wg1[32*136]=4352 | s_wg2[32*40]=1280  (14336)
    //  main  : s_whh[192*72]=13824 | s_wo1[32*72]=2304                      (16128)
    __shared__ __align__(16) f16 s_mem[16128];

    const int tid = threadIdx.x;
    const int wv = tid >> 6, ln = tid & 63;
    const int a = ln & 15, g = ln >> 4;
    const int row0 = blockIdx.x * 64 + wv * 16;

    const f32x4 ZF = {0.f, 0.f, 0.f, 0.f};

    f16* s_wp  = s_mem;            // phase 1
    f16* s_wg1 = s_mem + 8704;
    f16* s_wg2 = s_mem + 13056;

    // ---- stage phase-1 weights (f16) ----
    for (int i = tid; i < 64 * 128; i += TPB) s_wp [(i >> 7) * 136 + (i & 127)] = (f16)Wp[i];
    for (int i = tid; i < 32 * 128; i += TPB) s_wg1[(i >> 7) * 136 + (i & 127)] = (f16)Wg1[i];
    for (int i = tid; i < 32 * 32; i += TPB) {
        int t = i >> 5, s = i & 31;
        int q = ((s >> 2) & 1) * 16 + ((s >> 3) & 3) * 4 + (s & 3);   // sigma''
        s_wg2[t * 40 + s] = (f16)((t < HOR) ? Wg2[t * 32 + q] : 0.0f);
    }

    // ---- per-lane packed constants (unit u = 16c + 4g + r) ----
    f16x2 wR[4][2], wZ[4][2], wN[4][2], bR[4][2], bZ[4][2], bN[4][2], bH[4][2];
    #pragma unroll
    for (int c = 0; c < 4; ++c) {
        #pragma unroll
        for (int p = 0; p < 2; ++p) {
            int u0 = c * 16 + g * 4 + 2 * p, u1 = u0 + 1;
            wR[c][p] = pk2(W_ih[u0] * -LOG2E, W_ih[u1] * -LOG2E);
            wZ[c][p] = pk2(W_ih[64 + u0] * -LOG2E, W_ih[64 + u1] * -LOG2E);
            wN[c][p] = pk2(W_ih[128 + u0] * 2.0f * LOG2E, W_ih[128 + u1] * 2.0f * LOG2E);
            bR[c][p] = pk2((b_ih[u0] + b_hh[u0]) * -LOG2E, (b_ih[u1] + b_hh[u1]) * -LOG2E);
            bZ[c][p] = pk2((b_ih[64 + u0] + b_hh[64 + u0]) * -LOG2E,
                           (b_ih[64 + u1] + b_hh[64 + u1]) * -LOG2E);
            bN[c][p] = pk2(b_ih[128 + u0] * 2.0f * LOG2E, b_ih[128 + u1] * 2.0f * LOG2E);
            bH[c][p] = pk2(b_hh[128 + u0] * 2.0f * LOG2E, b_hh[128 + u1] * 2.0f * LOG2E);
        }
    }
    f16x2 bo1q[2][2], wo2q[2][2];
    #pragma unroll
    for (int mt = 0; mt < 2; ++mt)
        #pragma unroll
        for (int p = 0; p < 2; ++p) {
            int q0 = mt * 16 + g * 4 + 2 * p;
            bo1q[mt][p] = pk2(bo1[q0], bo1[q0 + 1]);
            wo2q[mt][p] = pk2(Wo2[q0], Wo2[q0 + 1]);
        }
    const float bo2v = bo2[0];
    const float edc  = LOG2E * __builtin_amdgcn_exp2f(LOG2E * log_decay[0]);
    const float lv   = last_value[row0 + a];

    // ---- feature fragments (f16, natural k order) ----
    V8 FF[4];
    #pragma unroll
    for (int kt = 0; kt < 4; ++kt) {
        const float* fp = features + (size_t)(row0 + a) * 128 + kt * 32 + g * 8;
        f32x4 v0 = *(const f32x4*)fp;
        f32x4 v1 = *(const f32x4*)(fp + 4);
        FF[kt].h2[0] = pk2(v0[0], v0[1]); FF[kt].h2[1] = pk2(v0[2], v0[3]);
        FF[kt].h2[2] = pk2(v1[0], v1[1]); FF[kt].h2[3] = pk2(v1[2], v1[3]);
    }

    __syncthreads();

    // ---- h0 = feat @ Wp^T + bp : lane(a,g) reg r -> batch a, unit 16nt+4g+r ----
    f32x4 h4[4];
    {
        f16x2 bpq[4][2];
        #pragma unroll
        for (int c = 0; c < 4; ++c)
            #pragma unroll
            for (int p = 0; p < 2; ++p) {
                int u0 = c * 16 + g * 4 + 2 * p;
                bpq[c][p] = pk2(bp[u0], bp[u0 + 1]);
            }
        #pragma unroll
        for (int nt = 0; nt < 4; ++nt) {
            f32x4 acc = ZF;
            #pragma unroll
            for (int kt = 0; kt < 4; ++kt) {
                f16x8 w = *(const f16x8*)&s_wp[(nt * 16 + a) * 136 + kt * 32 + g * 8];
                acc = MFMA16(w, FF[kt].v8, acc);
            }
            #pragma unroll
            for (int r = 0; r < 4; ++r) acc[r] += (float)bpq[nt][r >> 1][r & 1];
            h4[nt] = acc;
        }
    }

    // ---- gate path ----
    float gA0, gA1, gA2, gA3, gB0, gB1, gB2, gB3;
    {
        f32x4 a1acc[2];
        #pragma unroll
        for (int mt = 0; mt < 2; ++mt) {
            f32x4 acc = ZF;
            #pragma unroll
            for (int kt = 0; kt < 4; ++kt) {
                f16x8 w = *(const f16x8*)&s_wg1[(mt * 16 + a) * 136 + kt * 32 + g * 8];
                acc = MFMA16(w, FF[kt].v8, acc);
            }
            #pragma unroll
            for (int r = 0; r < 4; ++r) {
                int q0 = mt * 16 + g * 4 + r;
                acc[r] = fmaxf(acc[r] + bg1[q0], 0.f);
            }
            a1acc[mt] = acc;
        }
        V8 A1;
        A1.h2[0] = pk2(a1acc[0][0], a1acc[0][1]);
        A1.h2[1] = pk2(a1acc[0][2], a1acc[0][3]);
        A1.h2[2] = pk2(a1acc[1][0], a1acc[1][1]);
        A1.h2[3] = pk2(a1acc[1][2], a1acc[1][3]);
        float gv[2][4];
        #pragma unroll
        for (int mt = 0; mt < 2; ++mt) {
            f32x4 acc = ZF;
            f16x8 w = *(const f16x8*)&s_wg2[(mt * 16 + a) * 40 + g * 8];
            acc = MFMA16(w, A1.v8, acc);
            #pragma unroll
            for (int r = 0; r < 4; ++r) {
                int t0 = mt * 16 + g * 4 + r;
                float lg = acc[r] + ((t0 < HOR) ? bg2[t0] : 0.f);
                gv[mt][r] = __builtin_amdgcn_rcpf(1.0f + __builtin_amdgcn_exp2f(-LOG2E * lg));
            }
        }
        gA0 = gv[0][0]; gA1 = gv[0][1]; gA2 = gv[0][2]; gA3 = gv[0][3];
        gB0 = gv[1][0]; gB1 = gv[1][1]; gB2 = gv[1][2]; gB3 = gv[1][3];
    }

    // ---- restage: main-loop weights into the union region ----
    __syncthreads();
    f16* s_whh = s_mem;             // [192][72], scaled
    f16* s_wo1 = s_mem + 13824;     // [32][72]
    for (int i = tid; i < 192 * 64; i += TPB) {
        int r = i >> 6, c = i & 63;
        float s = (r < 128) ? -LOG2E : 2.0f * LOG2E;
        s_whh[r * 72 + c] = (f16)(W_hh[i] * s);
    }
    for (int i = tid; i < 32 * 64; i += TPB) s_wo1[(i >> 6) * 72 + (i & 63)] = (f16)Wo1[i];
    __syncthreads();

    // ---- loop-invariant W_hh fragments into registers (sigma cols) ----
    V8 WgR[4][2], WgZ[4][2], WgN[4][2];
    #pragma unroll
    for (int c = 0; c < 4; ++c) {
        #pragma unroll
        for (int kt = 0; kt < 2; ++kt) {
            int rowR = (c * 16 + a) * 72 + kt * 32 + 4 * g;
            int rowZ = (64 + c * 16 + a) * 72 + kt * 32 + 4 * g;
            int rowN = (128 + c * 16 + a) * 72 + kt * 32 + 4 * g;
            WgR[c][kt].v4[0] = *(const f16x4*)&s_whh[rowR];
            WgR[c][kt].v4[1] = *(const f16x4*)&s_whh[rowR + 16];
            WgZ[c][kt].v4[0] = *(const f16x4*)&s_whh[rowZ];
            WgZ[c][kt].v4[1] = *(const f16x4*)&s_whh[rowZ + 16];
            WgN[c][kt].v4[0] = *(const f16x4*)&s_whh[rowN];
            WgN[c][kt].v4[1] = *(const f16x4*)&s_whh[rowN + 16];
        }
    }

    // ---- pack initial h fragments ----
    V8 F0, F1;
    F0.h2[0] = pk2(h4[0][0], h4[0][1]); F0.h2[1] = pk2(h4[0][2], h4[0][3]);
    F0.h2[2] = pk2(h4[1][0], h4[1][1]); F0.h2[3] = pk2(h4[1][2], h4[1][3]);
    F1.h2[0] = pk2(h4[2][0], h4[2][1]); F1.h2[1] = pk2(h4[2][2], h4[2][3]);
    F1.h2[2] = pk2(h4[3][0], h4[3][1]); F1.h2[3] = pk2(h4[3][2], h4[3][3]);

    float x = lv;

#define GATE_MMA(ACC, WARR, c) do { \
        ACC = MFMA16(WARR[c][0].v8, F0.v8, ZF); \
        ACC = MFMA16(WARR[c][1].v8, F1.v8, ACC); } while (0)

#define GRU_CELL(c, AR, AZ, AN) do { \
        _Pragma("unroll") \
        for (int p = 0; p < 2; ++p) { \
            f16x2 afR = x2 * wR[c][p] + bR[c][p]; \
            f16x2 afZ = x2 * wZ[c][p] + bZ[c][p]; \
            f16x2 afN = x2 * wN[c][p] + bN[c][p]; \
            _Pragma("unroll") \
            for (int q = 0; q < 2; ++q) { \
                int r = p * 2 + q; \
                float ar = AR[r] + (float)afR[q]; \
                float rg = __builtin_amdgcn_rcpf(1.0f + __builtin_amdgcn_exp2f(ar)); \
                float az = AZ[r] + (float)afZ[q]; \
                float pb = 1.0f + __builtin_amdgcn_exp2f(az); \
                float ghn = AN[r] + (float)bH[c][p][q]; \
                float E  = __builtin_amdgcn_exp2f(fmaf(rg, ghn, (float)afN[q])); \
                float pE = 1.0f + E; \
                float rD = __builtin_amdgcn_rcpf(pb * pE); \
                float zg = rD * pE; \
                float ivE = rD * pb; \
                float nc = fmaf(-2.0f, ivE, 1.0f); \
                float hv = h4[c][r]; \
                h4[c][r] = fmaf(zg, hv - nc, nc); \
            } \
        } } while (0)

    #pragma unroll 1
    for (int t = 0; t < HOR; ++t) {
        f16x2 x2 = pk2(x, x);
        f32x4 aR0, aZ0, aN0, aR1, aZ1, aN1;
        // half 0: unit classes c=0,1
        GATE_MMA(aR0, WgR, 0); GATE_MMA(aZ0, WgZ, 0); GATE_MMA(aN0, WgN, 0);
        GATE_MMA(aR1, WgR, 1); GATE_MMA(aZ1, WgZ, 1); GATE_MMA(aN1, WgN, 1);
        GRU_CELL(0, aR0, aZ0, aN0);
        GRU_CELL(1, aR1, aZ1, aN1);
        // half 1: c=2,3 (reuse acc registers)
        GATE_MMA(aR0, WgR, 2); GATE_MMA(aZ0, WgZ, 2); GATE_MMA(aN0, WgN, 2);
        GATE_MMA(aR1, WgR, 3); GATE_MMA(aZ1, WgZ, 3); GATE_MMA(aN1, WgN, 3);
        GRU_CELL(2, aR0, aZ0, aN0);
        GRU_CELL(3, aR1, aZ1, aN1);

        // pack new h fragments (in-lane, sigma makes this local)
        F0.h2[0] = pk2(h4[0][0], h4[0][1]); F0.h2[1] = pk2(h4[0][2], h4[0][3]);
        F0.h2[2] = pk2(h4[1][0], h4[1][1]); F0.h2[3] = pk2(h4[1][2], h4[1][3]);
        F1.h2[0] = pk2(h4[2][0], h4[2][1]); F1.h2[1] = pk2(h4[2][2], h4[2][3]);
        F1.h2[2] = pk2(h4[3][0], h4[3][1]); F1.h2[3] = pk2(h4[3][2], h4[3][3]);

        // head: o = relu(h@Wo1^T + bo1) @ Wo2^T + bo2  (Wo1 frags from LDS, sigma cols)
        V8 wo;
        f32x4 o0 = ZF, o1 = ZF;
        wo.v4[0] = *(const f16x4*)&s_wo1[a * 72 + 4 * g];
        wo.v4[1] = *(const f16x4*)&s_wo1[a * 72 + 16 + 4 * g];
        o0 = MFMA16(wo.v8, F0.v8, o0);
        wo.v4[0] = *(const f16x4*)&s_wo1[a * 72 + 32 + 4 * g];
        wo.v4[1] = *(const f16x4*)&s_wo1[a * 72 + 48 + 4 * g];
        o0 = MFMA16(wo.v8, F1.v8, o0);
        wo.v4[0] = *(const f16x4*)&s_wo1[(16 + a) * 72 + 4 * g];
        wo.v4[1] = *(const f16x4*)&s_wo1[(16 + a) * 72 + 16 + 4 * g];
        o1 = MFMA16(wo.v8, F0.v8, o1);
        wo.v4[0] = *(const f16x4*)&s_wo1[(16 + a) * 72 + 32 + 4 * g];
        wo.v4[1] = *(const f16x4*)&s_wo1[(16 + a) * 72 + 48 + 4 * g];
        o1 = MFMA16(wo.v8, F1.v8, o1);

        float part = 0.f;
        #pragma unroll
        for (int p = 0; p < 2; ++p)
            #pragma unroll
            for (int q = 0; q < 2; ++q) {
                int r = 2 * p + q;
                part += fmaxf(o0[r] + (float)bo1q[0][p][q], 0.f) * (float)wo2q[0][p][q];
                part += fmaxf(o1[r] + (float)bo1q[1][p][q], 0.f) * (float)wo2q[1][p][q];
            }
        part += __shfl_xor(part, 16);
        part += __shfl_xor(part, 32);
        float pred = part + bo2v;

        // blend + store: one g-subgroup owns column t
        if (g == ((t >> 2) & 3)) {
            float s01 = (t & 1) ? ((t & 16) ? gB1 : gA1) : ((t & 16) ? gB0 : gA0);
            float s23 = (t & 1) ? ((t & 16) ? gB3 : gA3) : ((t & 16) ? gB2 : gA2);
            float gvf = (t & 2) ? s23 : s01;
            float dc = __builtin_amdgcn_exp2f(-edc * (float)(t + 1));
            float lvdc = lv * dc;
            out[(size_t)(row0 + a) * HOR + t] = fmaf(gvf, pred - lvdc, lvdc);
        }
        x = pred;
    }
#undef GATE_MMA
#undef GRU_CELL
}

extern "C" void kernel_launch(void* const* d_in, const int* in_sizes, int n_in,
                              void* d_out, int out_size, void* d_ws, size_t ws_size,
                              hipStream_t stream) {
    const float* features   = (const float*)d_in[0];
    const float* last_value = (const float*)d_in[1];
    const float* W_ih       = (const float*)d_in[2];
    const float* W_hh       = (const float*)d_in[3];
    const float* b_ih       = (const float*)d_in[4];
    const float* b_hh       = (const float*)d_in[5];
    const float* Wp         = (const float*)d_in[6];
    const float* bp         = (const float*)d_in[7];
    const float* Wo1        = (const float*)d_in[8];
    const float* bo1        = (const float*)d_in[9];
    const float* Wo2        = (const float*)d_in[10];
    const float* bo2        = (const float*)d_in[11];
    const float* Wg1        = (const float*)d_in[12];
    const float* bg1        = (const float*)d_in[13];
    const float* Wg2        = (const float*)d_in[14];
    const float* bg2        = (const float*)d_in[15];
    const float* log_decay  = (const float*)d_in[16];
    float* out = (float*)d_out;

    dim3 grid(131072 / 64), block(TPB);
    predictor_kernel<<<grid, block, 0, stream>>>(
        features, last_value, W_ih, W_hh, b_ih, b_hh, Wp, bp,
        Wo1, bo1, Wo2, bo2, Wg1, bg1, Wg2, bg2, log_decay, out);
}

// Round 7
// 243.841 us; speedup vs baseline: 4.7605x; 4.7605x over previous
//
#include <hip/hip_runtime.h>

#define TPB 256
#define HOR 28
#define LOG2E 1.44269504088896340736f

typedef _Float16 f16;
typedef __attribute__((ext_vector_type(2))) _Float16 f16x2;
typedef __attribute__((ext_vector_type(4))) _Float16 f16x4;
typedef __attribute__((ext_vector_type(8))) _Float16 f16x8;
typedef __attribute__((ext_vector_type(4))) float f32x4;

union V8 { f16x8 v8; f16x4 v4[2]; f16x2 h2[4]; };

#define MFMA16(A,B,C) __builtin_amdgcn_mfma_f32_16x16x32_f16((A),(B),(C),0,0,0)

__device__ __forceinline__ f16x2 pk2(float a, float b) {
    return __builtin_bit_cast(f16x2, __builtin_amdgcn_cvt_pkrtz(a, b));
}

__global__ __launch_bounds__(TPB, 2) void predictor_kernel(
    const float* __restrict__ features,
    const float* __restrict__ last_value,
    const float* __restrict__ W_ih,
    const float* __restrict__ W_hh,
    const float* __restrict__ b_ih,
    const float* __restrict__ b_hh,
    const float* __restrict__ Wp,
    const float* __restrict__ bp,
    const float* __restrict__ Wo1,
    const float* __restrict__ bo1,
    const float* __restrict__ Wo2,
    const float* __restrict__ bo2,
    const float* __restrict__ Wg1,
    const float* __restrict__ bg1,
    const float* __restrict__ Wg2,
    const float* __restrict__ bg2,
    const float* __restrict__ log_decay,
    float* __restrict__ out)
{
    // 32256 B f16 union region (-> LDS no longer the occupancy limiter):
    //  phase1: s_wp[64*136]=8704 | s_wg1[32*136]=4352 | s_wg2[32*40]=1280  (14336)
    //  main  : s_whh[192*72]=13824 | s_wo1[32*72]=2304                      (16128)
    __shared__ __align__(16) f16 s_mem[16128];

    const int tid = threadIdx.x;
    const int wv = tid >> 6, ln = tid & 63;
    const int a = ln & 15, g = ln >> 4;
    const int row0 = blockIdx.x * 64 + wv * 16;

    const f32x4 ZF = {0.f, 0.f, 0.f, 0.f};

    f16* s_wp  = s_mem;            // phase 1
    f16* s_wg1 = s_mem + 8704;
    f16* s_wg2 = s_mem + 13056;

    // ---- stage phase-1 weights (f16) ----
    for (int i = tid; i < 64 * 128; i += TPB) s_wp [(i >> 7) * 136 + (i & 127)] = (f16)Wp[i];
    for (int i = tid; i < 32 * 128; i += TPB) s_wg1[(i >> 7) * 136 + (i & 127)] = (f16)Wg1[i];
    for (int i = tid; i < 32 * 32; i += TPB) {
        int t = i >> 5, s = i & 31;
        int q = ((s >> 2) & 1) * 16 + ((s >> 3) & 3) * 4 + (s & 3);   // sigma''
        s_wg2[t * 40 + s] = (f16)((t < HOR) ? Wg2[t * 32 + q] : 0.0f);
    }

    // ---- per-lane packed constants (unit u = 16c + 4g + r) ----
    f16x2 wR[4][2], wZ[4][2], wN[4][2], bR[4][2], bZ[4][2], bN[4][2], bH[4][2];
    #pragma unroll
    for (int c = 0; c < 4; ++c) {
        #pragma unroll
        for (int p = 0; p < 2; ++p) {
            int u0 = c * 16 + g * 4 + 2 * p, u1 = u0 + 1;
            wR[c][p] = pk2(W_ih[u0] * -LOG2E, W_ih[u1] * -LOG2E);
            wZ[c][p] = pk2(W_ih[64 + u0] * -LOG2E, W_ih[64 + u1] * -LOG2E);
            wN[c][p] = pk2(W_ih[128 + u0] * 2.0f * LOG2E, W_ih[128 + u1] * 2.0f * LOG2E);
            bR[c][p] = pk2((b_ih[u0] + b_hh[u0]) * -LOG2E, (b_ih[u1] + b_hh[u1]) * -LOG2E);
            bZ[c][p] = pk2((b_ih[64 + u0] + b_hh[64 + u0]) * -LOG2E,
                           (b_ih[64 + u1] + b_hh[64 + u1]) * -LOG2E);
            bN[c][p] = pk2(b_ih[128 + u0] * 2.0f * LOG2E, b_ih[128 + u1] * 2.0f * LOG2E);
            bH[c][p] = pk2(b_hh[128 + u0] * 2.0f * LOG2E, b_hh[128 + u1] * 2.0f * LOG2E);
        }
    }
    f16x2 bo1q[2][2], wo2q[2][2];
    #pragma unroll
    for (int mt = 0; mt < 2; ++mt)
        #pragma unroll
        for (int p = 0; p < 2; ++p) {
            int q0 = mt * 16 + g * 4 + 2 * p;
            bo1q[mt][p] = pk2(bo1[q0], bo1[q0 + 1]);
            wo2q[mt][p] = pk2(Wo2[q0], Wo2[q0 + 1]);
        }
    const float bo2v = bo2[0];
    const float edc  = LOG2E * __builtin_amdgcn_exp2f(LOG2E * log_decay[0]);
    const float lv   = last_value[row0 + a];

    // ---- feature fragments (f16, natural k order) ----
    V8 FF[4];
    #pragma unroll
    for (int kt = 0; kt < 4; ++kt) {
        const float* fp = features + (size_t)(row0 + a) * 128 + kt * 32 + g * 8;
        f32x4 v0 = *(const f32x4*)fp;
        f32x4 v1 = *(const f32x4*)(fp + 4);
        FF[kt].h2[0] = pk2(v0[0], v0[1]); FF[kt].h2[1] = pk2(v0[2], v0[3]);
        FF[kt].h2[2] = pk2(v1[0], v1[1]); FF[kt].h2[3] = pk2(v1[2], v1[3]);
    }

    __syncthreads();

    // ---- h0 = feat @ Wp^T + bp : lane(a,g) reg r -> batch a, unit 16nt+4g+r ----
    f32x4 h4[4];
    {
        f16x2 bpq[4][2];
        #pragma unroll
        for (int c = 0; c < 4; ++c)
            #pragma unroll
            for (int p = 0; p < 2; ++p) {
                int u0 = c * 16 + g * 4 + 2 * p;
                bpq[c][p] = pk2(bp[u0], bp[u0 + 1]);
            }
        #pragma unroll
        for (int nt = 0; nt < 4; ++nt) {
            f32x4 acc = ZF;
            #pragma unroll
            for (int kt = 0; kt < 4; ++kt) {
                f16x8 w = *(const f16x8*)&s_wp[(nt * 16 + a) * 136 + kt * 32 + g * 8];
                acc = MFMA16(w, FF[kt].v8, acc);
            }
            #pragma unroll
            for (int r = 0; r < 4; ++r) acc[r] += (float)bpq[nt][r >> 1][r & 1];
            h4[nt] = acc;
        }
    }

    // ---- gate path ----
    float gA0, gA1, gA2, gA3, gB0, gB1, gB2, gB3;
    {
        f32x4 a1acc[2];
        #pragma unroll
        for (int mt = 0; mt < 2; ++mt) {
            f32x4 acc = ZF;
            #pragma unroll
            for (int kt = 0; kt < 4; ++kt) {
                f16x8 w = *(const f16x8*)&s_wg1[(mt * 16 + a) * 136 + kt * 32 + g * 8];
                acc = MFMA16(w, FF[kt].v8, acc);
            }
            #pragma unroll
            for (int r = 0; r < 4; ++r) {
                int q0 = mt * 16 + g * 4 + r;
                acc[r] = fmaxf(acc[r] + bg1[q0], 0.f);
            }
            a1acc[mt] = acc;
        }
        V8 A1;
        A1.h2[0] = pk2(a1acc[0][0], a1acc[0][1]);
        A1.h2[1] = pk2(a1acc[0][2], a1acc[0][3]);
        A1.h2[2] = pk2(a1acc[1][0], a1acc[1][1]);
        A1.h2[3] = pk2(a1acc[1][2], a1acc[1][3]);
        float gv[2][4];
        #pragma unroll
        for (int mt = 0; mt < 2; ++mt) {
            f32x4 acc = ZF;
            f16x8 w = *(const f16x8*)&s_wg2[(mt * 16 + a) * 40 + g * 8];
            acc = MFMA16(w, A1.v8, acc);
            #pragma unroll
            for (int r = 0; r < 4; ++r) {
                int t0 = mt * 16 + g * 4 + r;
                float lg = acc[r] + ((t0 < HOR) ? bg2[t0] : 0.f);
                gv[mt][r] = __builtin_amdgcn_rcpf(1.0f + __builtin_amdgcn_exp2f(-LOG2E * lg));
            }
        }
        gA0 = gv[0][0]; gA1 = gv[0][1]; gA2 = gv[0][2]; gA3 = gv[0][3];
        gB0 = gv[1][0]; gB1 = gv[1][1]; gB2 = gv[1][2]; gB3 = gv[1][3];
    }

    // ---- restage: main-loop weights into the union region ----
    __syncthreads();
    f16* s_whh = s_mem;             // [192][72], scaled
    f16* s_wo1 = s_mem + 13824;     // [32][72]
    for (int i = tid; i < 192 * 64; i += TPB) {
        int r = i >> 6, c = i & 63;
        float s = (r < 128) ? -LOG2E : 2.0f * LOG2E;
        s_whh[r * 72 + c] = (f16)(W_hh[i] * s);
    }
    for (int i = tid; i < 32 * 64; i += TPB) s_wo1[(i >> 6) * 72 + (i & 63)] = (f16)Wo1[i];
    __syncthreads();

    // ---- loop-invariant W_hh fragments into registers (sigma cols) ----
    V8 WgR[4][2], WgZ[4][2], WgN[4][2];
    #pragma unroll
    for (int c = 0; c < 4; ++c) {
        #pragma unroll
        for (int kt = 0; kt < 2; ++kt) {
            int rowR = (c * 16 + a) * 72 + kt * 32 + 4 * g;
            int rowZ = (64 + c * 16 + a) * 72 + kt * 32 + 4 * g;
            int rowN = (128 + c * 16 + a) * 72 + kt * 32 + 4 * g;
            WgR[c][kt].v4[0] = *(const f16x4*)&s_whh[rowR];
            WgR[c][kt].v4[1] = *(const f16x4*)&s_whh[rowR + 16];
            WgZ[c][kt].v4[0] = *(const f16x4*)&s_whh[rowZ];
            WgZ[c][kt].v4[1] = *(const f16x4*)&s_whh[rowZ + 16];
            WgN[c][kt].v4[0] = *(const f16x4*)&s_whh[rowN];
            WgN[c][kt].v4[1] = *(const f16x4*)&s_whh[rowN + 16];
        }
    }

    // ---- pack initial h fragments ----
    V8 F0, F1;
    F0.h2[0] = pk2(h4[0][0], h4[0][1]); F0.h2[1] = pk2(h4[0][2], h4[0][3]);
    F0.h2[2] = pk2(h4[1][0], h4[1][1]); F0.h2[3] = pk2(h4[1][2], h4[1][3]);
    F1.h2[0] = pk2(h4[2][0], h4[2][1]); F1.h2[1] = pk2(h4[2][2], h4[2][3]);
    F1.h2[2] = pk2(h4[3][0], h4[3][1]); F1.h2[3] = pk2(h4[3][2], h4[3][3]);

    float x = lv;

#define GATE_MMA(ACC, WARR, c) do { \
        ACC = MFMA16(WARR[c][0].v8, F0.v8, ZF); \
        ACC = MFMA16(WARR[c][1].v8, F1.v8, ACC); } while (0)

#define GRU_CELL(c, AR, AZ, AN) do { \
        _Pragma("unroll") \
        for (int p = 0; p < 2; ++p) { \
            f16x2 afR = x2 * wR[c][p] + bR[c][p]; \
            f16x2 afZ = x2 * wZ[c][p] + bZ[c][p]; \
            f16x2 afN = x2 * wN[c][p] + bN[c][p]; \
            _Pragma("unroll") \
            for (int q = 0; q < 2; ++q) { \
                int r = p * 2 + q; \
                float ar = AR[r] + (float)afR[q]; \
                float rg = __builtin_amdgcn_rcpf(1.0f + __builtin_amdgcn_exp2f(ar)); \
                float az = AZ[r] + (float)afZ[q]; \
                float pb = 1.0f + __builtin_amdgcn_exp2f(az); \
                float ghn = AN[r] + (float)bH[c][p][q]; \
                float E  = __builtin_amdgcn_exp2f(fmaf(rg, ghn, (float)afN[q])); \
                float pE = 1.0f + E; \
                float rD = __builtin_amdgcn_rcpf(pb * pE); \
                float zg = rD * pE; \
                float ivE = rD * pb; \
                float nc = fmaf(-2.0f, ivE, 1.0f); \
                float hv = h4[c][r]; \
                h4[c][r] = fmaf(zg, hv - nc, nc); \
            } \
        } } while (0)

    #pragma unroll 1
    for (int t = 0; t < HOR; ++t) {
        f16x2 x2 = pk2(x, x);
        f32x4 aR0, aZ0, aN0, aR1, aZ1, aN1;
        // half 0: unit classes c=0,1
        GATE_MMA(aR0, WgR, 0); GATE_MMA(aZ0, WgZ, 0); GATE_MMA(aN0, WgN, 0);
        GATE_MMA(aR1, WgR, 1); GATE_MMA(aZ1, WgZ, 1); GATE_MMA(aN1, WgN, 1);
        GRU_CELL(0, aR0, aZ0, aN0);
        GRU_CELL(1, aR1, aZ1, aN1);
        // half 1: c=2,3 (reuse acc registers)
        GATE_MMA(aR0, WgR, 2); GATE_MMA(aZ0, WgZ, 2); GATE_MMA(aN0, WgN, 2);
        GATE_MMA(aR1, WgR, 3); GATE_MMA(aZ1, WgZ, 3); GATE_MMA(aN1, WgN, 3);
        GRU_CELL(2, aR0, aZ0, aN0);
        GRU_CELL(3, aR1, aZ1, aN1);

        // pack new h fragments (in-lane, sigma makes this local)
        F0.h2[0] = pk2(h4[0][0], h4[0][1]); F0.h2[1] = pk2(h4[0][2], h4[0][3]);
        F0.h2[2] = pk2(h4[1][0], h4[1][1]); F0.h2[3] = pk2(h4[1][2], h4[1][3]);
        F1.h2[0] = pk2(h4[2][0], h4[2][1]); F1.h2[1] = pk2(h4[2][2], h4[2][3]);
        F1.h2[2] = pk2(h4[3][0], h4[3][1]); F1.h2[3] = pk2(h4[3][2], h4[3][3]);

        // head: o = relu(h@Wo1^T + bo1) @ Wo2^T + bo2  (Wo1 frags from LDS, sigma cols)
        V8 wo;
        f32x4 o0 = ZF, o1 = ZF;
        wo.v4[0] = *(const f16x4*)&s_wo1[a * 72 + 4 * g];
        wo.v4[1] = *(const f16x4*)&s_wo1[a * 72 + 16 + 4 * g];
        o0 = MFMA16(wo.v8, F0.v8, o0);
        wo.v4[0] = *(const f16x4*)&s_wo1[a * 72 + 32 + 4 * g];
        wo.v4[1] = *(const f16x4*)&s_wo1[a * 72 + 48 + 4 * g];
        o0 = MFMA16(wo.v8, F1.v8, o0);
        wo.v4[0] = *(const f16x4*)&s_wo1[(16 + a) * 72 + 4 * g];
        wo.v4[1] = *(const f16x4*)&s_wo1[(16 + a) * 72 + 16 + 4 * g];
        o1 = MFMA16(wo.v8, F0.v8, o1);
        wo.v4[0] = *(const f16x4*)&s_wo1[(16 + a) * 72 + 32 + 4 * g];
        wo.v4[1] = *(const f16x4*)&s_wo1[(16 + a) * 72 + 48 + 4 * g];
        o1 = MFMA16(wo.v8, F1.v8, o1);

        float part = 0.f;
        #pragma unroll
        for (int p = 0; p < 2; ++p)
            #pragma unroll
            for (int q = 0; q < 2; ++q) {
                int r = 2 * p + q;
                part += fmaxf(o0[r] + (float)bo1q[0][p][q], 0.f) * (float)wo2q[0][p][q];
                part += fmaxf(o1[r] + (float)bo1q[1][p][q], 0.f) * (float)wo2q[1][p][q];
            }
        part += __shfl_xor(part, 16);
        part += __shfl_xor(part, 32);
        float pred = part + bo2v;

        // blend + store: one g-subgroup owns column t
        if (g == ((t >> 2) & 3)) {
            float s01 = (t & 1) ? ((t & 16) ? gB1 : gA1) : ((t & 16) ? gB0 : gA0);
            float s23 = (t & 1) ? ((t & 16) ? gB3 : gA3) : ((t & 16) ? gB2 : gA2);
            float gvf = (t & 2) ? s23 : s01;
            float dc = __builtin_amdgcn_exp2f(-edc * (float)(t + 1));
            float lvdc = lv * dc;
            out[(size_t)(row0 + a) * HOR + t] = fmaf(gvf, pred - lvdc, lvdc);
        }
        x = pred;
    }
#undef GATE_MMA
#undef GRU_CELL
}

extern "C" void kernel_launch(void* const* d_in, const int* in_sizes, int n_in,
                              void* d_out, int out_size, void* d_ws, size_t ws_size,
                              hipStream_t stream) {
    const float* features   = (const float*)d_in[0];
    const float* last_value = (const float*)d_in[1];
    const float* W_ih       = (const float*)d_in[2];
    const float* W_hh       = (const float*)d_in[3];
    const float* b_ih       = (const float*)d_in[4];
    const float* b_hh       = (const float*)d_in[5];
    const float* Wp         = (const float*)d_in[6];
    const float* bp         = (const float*)d_in[7];
    const float* Wo1        = (const float*)d_in[8];
    const float* bo1        = (const float*)d_in[9];
    const float* Wo2        = (const float*)d_in[10];
    const float* bo2        = (const float*)d_in[11];
    const float* Wg1        = (const float*)d_in[12];
    const float* bg1        = (const float*)d_in[13];
    const float* Wg2        = (const float*)d_in[14];
    const float* bg2        = (const float*)d_in[15];
    const float* log_decay  = (const float*)d_in[16];
    float* out = (float*)d_out;

    dim3 grid(131072 / 64), block(TPB);
    predictor_kernel<<<grid, block, 0, stream>>>(
        features, last_value, W_ih, W_hh, b_ih, b_hh, Wp, bp,
        Wo1, bo1, Wo2, bo2, Wg1, bg1, Wg2, bg2, log_decay, out);
}